// Round 6
// baseline (221.240 us; speedup 1.0000x reference)
//
#include <hip/hip_runtime.h>

#define F0 128
#define F1 64
#define F2 32

// ================= CSR build =================
__global__ void count_deg(const int* __restrict__ col, int* cnt, int E) {
    int e = blockIdx.x * 256 + threadIdx.x;
    if (e < E) atomicAdd(&cnt[col[e]], 1);
}

__global__ void scan_partial(const int* __restrict__ cnt, int* __restrict__ partial, int N) {
    __shared__ int red[256];
    int i = blockIdx.x * 256 + threadIdx.x;
    red[threadIdx.x] = (i < N) ? cnt[i] : 0;
    __syncthreads();
    for (int off = 128; off; off >>= 1) {
        if (threadIdx.x < off) red[threadIdx.x] += red[threadIdx.x + off];
        __syncthreads();
    }
    if (threadIdx.x == 0) partial[blockIdx.x] = red[0];
}

__global__ __launch_bounds__(1024) void scan_block(int* partial, int nb) {
    __shared__ int s[1024];
    int t = threadIdx.x;
    int v = (t < nb) ? partial[t] : 0;
    s[t] = v;
    __syncthreads();
    for (int off = 1; off < 1024; off <<= 1) {
        int u = (t >= off) ? s[t - off] : 0;
        __syncthreads();
        s[t] += u;
        __syncthreads();
    }
    if (t < nb) partial[t] = s[t] - v;
}

// cur may alias cnt: each element read once before any write.
__global__ void scan_final(const int* __restrict__ cnt, const int* __restrict__ partial,
                           int* __restrict__ ptr, int* __restrict__ cur,
                           float* __restrict__ dinv, int N, int E) {
    __shared__ int s[256];
    int t = threadIdx.x;
    int i = blockIdx.x * 256 + t;
    int v = (i < N) ? cnt[i] : 0;
    s[t] = v;
    __syncthreads();
    for (int off = 1; off < 256; off <<= 1) {
        int u = (t >= off) ? s[t - off] : 0;
        __syncthreads();
        s[t] += u;
        __syncthreads();
    }
    if (i < N) {
        int p = partial[blockIdx.x] + s[t] - v;
        ptr[i] = p;
        cur[i] = p;
        dinv[i] = rsqrtf((float)(v + 1));
    } else if (i == N) {
        ptr[N] = E;
    }
}

// counting-sort fill, 4B records: erow[pos] = row. norm computed at agg time.
__global__ void edge_fill(const int* __restrict__ row, const int* __restrict__ col,
                          int* cur, int* __restrict__ erow, int E) {
    int e = blockIdx.x * 256 + threadIdx.x;
    if (e >= E) return;
    int c = col[e];
    int pos = atomicAdd(&cur[c], 1);
    erow[pos] = row[e];
}

// ================= register-tiled GEMMs =================
__device__ __forceinline__ void fma4(float4& a, float xs, const float4& wv) {
    a.x = fmaf(xs, wv.x, a.x);
    a.y = fmaf(xs, wv.y, a.y);
    a.z = fmaf(xs, wv.z, a.z);
    a.w = fmaf(xs, wv.w, a.w);
}

// gemm1: xw = x @ W1, tile 64 rows x 64 cols, thread = 4x4 micro-tile.
__global__ __launch_bounds__(256) void gemm1(const float* __restrict__ x,
                                             const float* __restrict__ W,
                                             float* __restrict__ xw, int N) {
    __shared__ float Xl[64 * F0];   // 32KB, swizzled
    __shared__ float Wl[F0 * F1];   // 32KB, linear [k][64]
    int tid = threadIdx.x;
    int base = blockIdx.x * 64;

    const float4* W4 = (const float4*)W;
    float4* Wl4 = (float4*)Wl;
#pragma unroll
    for (int i = 0; i < 8; ++i) Wl4[tid + 256 * i] = W4[tid + 256 * i];

    float4* Xl4 = (float4*)Xl;
#pragma unroll
    for (int i = 0; i < 8; ++i) {
        int idx = tid + 256 * i;
        int r = idx >> 5, c4 = idx & 31;
        int gr = base + r;
        float4 v = (gr < N) ? ((const float4*)x)[(size_t)gr * 32 + c4]
                            : make_float4(0.f, 0.f, 0.f, 0.f);
        Xl4[r * 32 + (c4 ^ (r >> 2))] = v;
    }
    __syncthreads();

    int tc = tid & 15, tr = tid >> 4;
    float4 acc0 = make_float4(0.f, 0.f, 0.f, 0.f);
    float4 acc1 = acc0, acc2 = acc0, acc3 = acc0;
    const float4* Wl4c = (const float4*)Wl;
    const float4* Xl4c = (const float4*)Xl;

#pragma unroll 4
    for (int kk = 0; kk < 32; ++kk) {
        float4 xv0 = Xl4c[(4 * tr + 0) * 32 + (kk ^ tr)];
        float4 xv1 = Xl4c[(4 * tr + 1) * 32 + (kk ^ tr)];
        float4 xv2 = Xl4c[(4 * tr + 2) * 32 + (kk ^ tr)];
        float4 xv3 = Xl4c[(4 * tr + 3) * 32 + (kk ^ tr)];
        float4 w0 = Wl4c[(4 * kk + 0) * 16 + tc];
        float4 w1 = Wl4c[(4 * kk + 1) * 16 + tc];
        float4 w2 = Wl4c[(4 * kk + 2) * 16 + tc];
        float4 w3 = Wl4c[(4 * kk + 3) * 16 + tc];
        fma4(acc0, xv0.x, w0); fma4(acc0, xv0.y, w1); fma4(acc0, xv0.z, w2); fma4(acc0, xv0.w, w3);
        fma4(acc1, xv1.x, w0); fma4(acc1, xv1.y, w1); fma4(acc1, xv1.z, w2); fma4(acc1, xv1.w, w3);
        fma4(acc2, xv2.x, w0); fma4(acc2, xv2.y, w1); fma4(acc2, xv2.z, w2); fma4(acc2, xv2.w, w3);
        fma4(acc3, xv3.x, w0); fma4(acc3, xv3.y, w1); fma4(acc3, xv3.z, w2); fma4(acc3, xv3.w, w3);
    }

    float4* xwo = (float4*)xw;
    int gr = base + 4 * tr;
    if (gr + 0 < N) xwo[(size_t)(gr + 0) * 16 + tc] = acc0;
    if (gr + 1 < N) xwo[(size_t)(gr + 1) * 16 + tc] = acc1;
    if (gr + 2 < N) xwo[(size_t)(gr + 2) * 16 + tc] = acc2;
    if (gr + 3 < N) xwo[(size_t)(gr + 3) * 16 + tc] = acc3;
}

// gemm2: hw = relu(h) @ W2, tile 128 rows x 32 cols, thread = 4x4 micro-tile.
__global__ __launch_bounds__(256) void gemm2(const float* __restrict__ h,
                                             const float* __restrict__ W,
                                             float* __restrict__ hw, int N) {
    __shared__ float Hl[128 * F1];  // 32KB, swizzled
    __shared__ float Wl[F1 * F2];   // 8KB
    int tid = threadIdx.x;
    int base = blockIdx.x * 128;

    const float4* W4 = (const float4*)W;
    float4* Wl4 = (float4*)Wl;
#pragma unroll
    for (int i = 0; i < 2; ++i) Wl4[tid + 256 * i] = W4[tid + 256 * i];

    float4* Hl4 = (float4*)Hl;
#pragma unroll
    for (int i = 0; i < 8; ++i) {
        int idx = tid + 256 * i;
        int r = idx >> 4, c4 = idx & 15;
        int gr = base + r;
        float4 v = (gr < N) ? ((const float4*)h)[(size_t)gr * 16 + c4]
                            : make_float4(0.f, 0.f, 0.f, 0.f);
        v.x = fmaxf(v.x, 0.f); v.y = fmaxf(v.y, 0.f);
        v.z = fmaxf(v.z, 0.f); v.w = fmaxf(v.w, 0.f);
        Hl4[r * 16 + (c4 ^ ((r >> 2) & 15))] = v;
    }
    __syncthreads();

    int tc = tid & 7, tr = tid >> 3;
    float4 acc0 = make_float4(0.f, 0.f, 0.f, 0.f);
    float4 acc1 = acc0, acc2 = acc0, acc3 = acc0;
    const float4* Wl4c = (const float4*)Wl;
    const float4* Hl4c = (const float4*)Hl;

#pragma unroll 4
    for (int kk = 0; kk < 16; ++kk) {
        int sw = kk ^ (tr & 15);
        float4 xv0 = Hl4c[(4 * tr + 0) * 16 + sw];
        float4 xv1 = Hl4c[(4 * tr + 1) * 16 + sw];
        float4 xv2 = Hl4c[(4 * tr + 2) * 16 + sw];
        float4 xv3 = Hl4c[(4 * tr + 3) * 16 + sw];
        float4 w0 = Wl4c[(4 * kk + 0) * 8 + tc];
        float4 w1 = Wl4c[(4 * kk + 1) * 8 + tc];
        float4 w2 = Wl4c[(4 * kk + 2) * 8 + tc];
        float4 w3 = Wl4c[(4 * kk + 3) * 8 + tc];
        fma4(acc0, xv0.x, w0); fma4(acc0, xv0.y, w1); fma4(acc0, xv0.z, w2); fma4(acc0, xv0.w, w3);
        fma4(acc1, xv1.x, w0); fma4(acc1, xv1.y, w1); fma4(acc1, xv1.z, w2); fma4(acc1, xv1.w, w3);
        fma4(acc2, xv2.x, w0); fma4(acc2, xv2.y, w1); fma4(acc2, xv2.z, w2); fma4(acc2, xv2.w, w3);
        fma4(acc3, xv3.x, w0); fma4(acc3, xv3.y, w1); fma4(acc3, xv3.z, w2); fma4(acc3, xv3.w, w3);
    }

    float4* hwo = (float4*)hw;
    int gr = base + 4 * tr;
    if (gr + 0 < N) hwo[(size_t)(gr + 0) * 8 + tc] = acc0;
    if (gr + 1 < N) hwo[(size_t)(gr + 1) * 8 + tc] = acc1;
    if (gr + 2 < N) hwo[(size_t)(gr + 2) * 8 + tc] = acc2;
    if (gr + 3 < N) hwo[(size_t)(gr + 3) * 8 + tc] = acc3;
}

// ================= layer 1 aggregation (gather): one wave per node =================
// acc = xw[i]*d_i + sum_e xw[row_e]*dinv[row_e];  out = acc*d_i + b
__global__ void agg1(const int* __restrict__ ptr, const int* __restrict__ erow,
                     const float* __restrict__ xw, const float* __restrict__ dinv,
                     const float* __restrict__ b, float* __restrict__ out, int N) {
    int t = blockIdx.x * 256 + threadIdx.x;
    int i = t >> 6, j = t & 63;
    if (i >= N) return;
    float d = dinv[i];
    float acc = xw[(size_t)i * F1 + j] * d;
    int e = ptr[i], end = ptr[i + 1];
    for (; e + 1 < end; e += 2) {
        int r0 = erow[e], r1 = erow[e + 1];
        float w0 = dinv[r0], w1 = dinv[r1];
        acc += xw[(size_t)r0 * F1 + j] * w0;
        acc += xw[(size_t)r1 * F1 + j] * w1;
    }
    if (e < end) {
        int r0 = erow[e];
        acc += xw[(size_t)r0 * F1 + j] * dinv[r0];
    }
    out[(size_t)i * F1 + j] = acc * d + b[j];
}

// ================= layer 2 aggregation + fused log_softmax =================
__global__ void agg2_lsm(const int* __restrict__ ptr, const int* __restrict__ erow,
                         const float* __restrict__ hw, const float* __restrict__ dinv,
                         const float* __restrict__ b, float* __restrict__ out, int N) {
    int t = blockIdx.x * 256 + threadIdx.x;
    int i = t >> 5, j = t & 31;
    if (i >= N) return;
    float d = dinv[i];
    float acc = hw[(size_t)i * F2 + j] * d;
    int e = ptr[i], end = ptr[i + 1];
    for (; e + 1 < end; e += 2) {
        int r0 = erow[e], r1 = erow[e + 1];
        float w0 = dinv[r0], w1 = dinv[r1];
        acc += hw[(size_t)r0 * F2 + j] * w0;
        acc += hw[(size_t)r1 * F2 + j] * w1;
    }
    if (e < end) {
        int r0 = erow[e];
        acc += hw[(size_t)r0 * F2 + j] * dinv[r0];
    }
    acc = acc * d + b[j];
    float m = acc;
    for (int off = 16; off; off >>= 1) m = fmaxf(m, __shfl_xor(m, off, 32));
    float s = expf(acc - m);
    for (int off = 16; off; off >>= 1) s += __shfl_xor(s, off, 32);
    out[(size_t)i * F2 + j] = acc - m - logf(s);
}

extern "C" void kernel_launch(void* const* d_in, const int* in_sizes, int n_in,
                              void* d_out, int out_size, void* d_ws, size_t ws_size,
                              hipStream_t stream) {
    const float* x  = (const float*)d_in[0];
    const int*   ei = (const int*)d_in[1];
    const float* W1 = (const float*)d_in[2];
    const float* b1 = (const float*)d_in[3];
    const float* W2 = (const float*)d_in[4];
    const float* b2 = (const float*)d_in[5];

    int N = in_sizes[0] / F0;
    int E = in_sizes[1] / 2;
    const int* row = ei;
    const int* col = ei + E;

    size_t Np = ((size_t)N + 63) & ~(size_t)63;
    size_t Ep = ((size_t)E + 63) & ~(size_t)63;
    int*   cnt     = (int*)d_ws;                 // Np (reused as cur)
    int*   ptr     = cnt + Np;                   // Np+64
    float* dinv    = (float*)(ptr + Np + 64);    // Np
    int*   partial = (int*)(dinv + Np);          // 1024
    int*   erow    = partial + 1024;             // Ep (4B records)
    float* xw1     = (float*)(erow + Ep);        // N*64 (reused as h2w)
    float* out1    = xw1 + (size_t)N * F1;       // N*64
    int*   cur     = cnt;
    float* h2w     = xw1;
    float* out2    = (float*)d_out;

    int nbN  = (N + 255) / 256;
    int nbN1 = (N + 256) / 256;
    int nbE  = (E + 255) / 256;

    hipMemsetAsync(cnt, 0, (size_t)N * sizeof(int), stream);
    count_deg<<<nbE, 256, 0, stream>>>(col, cnt, E);
    scan_partial<<<nbN, 256, 0, stream>>>(cnt, partial, N);
    scan_block<<<1, 1024, 0, stream>>>(partial, nbN);
    scan_final<<<nbN1, 256, 0, stream>>>(cnt, partial, ptr, cur, dinv, N, E);
    edge_fill<<<nbE, 256, 0, stream>>>(row, col, cur, erow, E);

    gemm1<<<(N + 63) / 64, 256, 0, stream>>>(x, W1, xw1, N);
    agg1<<<(int)(((size_t)N * F1 + 255) / 256), 256, 0, stream>>>(ptr, erow, xw1, dinv, b1, out1, N);

    gemm2<<<(N + 127) / 128, 256, 0, stream>>>(out1, W2, h2w, N);
    agg2_lsm<<<(int)(((size_t)N * F2 + 255) / 256), 256, 0, stream>>>(ptr, erow, h2w, dinv, b2, out2, N);
}

// Round 7
// 205.548 us; speedup vs baseline: 1.0763x; 1.0763x over previous
//
#include <hip/hip_runtime.h>

#define F0 128
#define F1 64
#define F2 32

typedef unsigned short ushort_t;
typedef unsigned int uint_t;

__device__ __forceinline__ ushort_t f2bf(float f) {   // f32 -> bf16 RNE
    uint_t u = __float_as_uint(f);
    return (ushort_t)((u + 0x7FFFu + ((u >> 16) & 1u)) >> 16);
}
__device__ __forceinline__ float bf2f(ushort_t u) {   // bf16 -> f32
    return __uint_as_float((uint_t)u << 16);
}

// ================= CSR build =================
__global__ void count_deg(const int* __restrict__ col, int* cnt, int E) {
    int e = blockIdx.x * 256 + threadIdx.x;
    if (e < E) atomicAdd(&cnt[col[e]], 1);
}

__global__ void scan_partial(const int* __restrict__ cnt, int* __restrict__ partial, int N) {
    __shared__ int red[256];
    int i = blockIdx.x * 256 + threadIdx.x;
    red[threadIdx.x] = (i < N) ? cnt[i] : 0;
    __syncthreads();
    for (int off = 128; off; off >>= 1) {
        if (threadIdx.x < off) red[threadIdx.x] += red[threadIdx.x + off];
        __syncthreads();
    }
    if (threadIdx.x == 0) partial[blockIdx.x] = red[0];
}

__global__ __launch_bounds__(1024) void scan_block(int* partial, int nb) {
    __shared__ int s[1024];
    int t = threadIdx.x;
    int v = (t < nb) ? partial[t] : 0;
    s[t] = v;
    __syncthreads();
    for (int off = 1; off < 1024; off <<= 1) {
        int u = (t >= off) ? s[t - off] : 0;
        __syncthreads();
        s[t] += u;
        __syncthreads();
    }
    if (t < nb) partial[t] = s[t] - v;
}

// cur may alias cnt: each element read once before any write.
__global__ void scan_final(const int* __restrict__ cnt, const int* __restrict__ partial,
                           int* __restrict__ ptr, int* __restrict__ cur,
                           float* __restrict__ dinv, int N, int E) {
    __shared__ int s[256];
    int t = threadIdx.x;
    int i = blockIdx.x * 256 + t;
    int v = (i < N) ? cnt[i] : 0;
    s[t] = v;
    __syncthreads();
    for (int off = 1; off < 256; off <<= 1) {
        int u = (t >= off) ? s[t - off] : 0;
        __syncthreads();
        s[t] += u;
        __syncthreads();
    }
    if (i < N) {
        int p = partial[blockIdx.x] + s[t] - v;
        ptr[i] = p;
        cur[i] = p;
        dinv[i] = rsqrtf((float)(v + 1));
    } else if (i == N) {
        ptr[N] = E;
    }
}

// counting-sort fill, 4B records, nontemporal scatter store.
__global__ void edge_fill(const int* __restrict__ row, const int* __restrict__ col,
                          int* cur, int* __restrict__ erow, int E) {
    int e = blockIdx.x * 256 + threadIdx.x;
    if (e >= E) return;
    int c = col[e];
    int r = row[e];
    int pos = atomicAdd(&cur[c], 1);
    __builtin_nontemporal_store(r, &erow[pos]);
}

// ================= register-tiled GEMMs =================
__device__ __forceinline__ void fma4(float4& a, float xs, const float4& wv) {
    a.x = fmaf(xs, wv.x, a.x);
    a.y = fmaf(xs, wv.y, a.y);
    a.z = fmaf(xs, wv.z, a.z);
    a.w = fmaf(xs, wv.w, a.w);
}

// gemm1: xwb = (x @ W1) * dinv[row], stored bf16. tile 64x64, thread = 4x4.
__global__ __launch_bounds__(256) void gemm1(const float* __restrict__ x,
                                             const float* __restrict__ W,
                                             const float* __restrict__ dinv,
                                             ushort_t* __restrict__ xwb, int N) {
    __shared__ float Xl[64 * F0];   // 32KB, swizzled
    __shared__ float Wl[F0 * F1];   // 32KB, linear [k][64]
    int tid = threadIdx.x;
    int base = blockIdx.x * 64;

    const float4* W4 = (const float4*)W;
    float4* Wl4 = (float4*)Wl;
#pragma unroll
    for (int i = 0; i < 8; ++i) Wl4[tid + 256 * i] = W4[tid + 256 * i];

    float4* Xl4 = (float4*)Xl;
#pragma unroll
    for (int i = 0; i < 8; ++i) {
        int idx = tid + 256 * i;
        int r = idx >> 5, c4 = idx & 31;
        int gr = base + r;
        float4 v = (gr < N) ? ((const float4*)x)[(size_t)gr * 32 + c4]
                            : make_float4(0.f, 0.f, 0.f, 0.f);
        Xl4[r * 32 + (c4 ^ (r >> 2))] = v;
    }
    __syncthreads();

    int tc = tid & 15, tr = tid >> 4;
    float4 acc0 = make_float4(0.f, 0.f, 0.f, 0.f);
    float4 acc1 = acc0, acc2 = acc0, acc3 = acc0;
    const float4* Wl4c = (const float4*)Wl;
    const float4* Xl4c = (const float4*)Xl;

#pragma unroll 4
    for (int kk = 0; kk < 32; ++kk) {
        float4 xv0 = Xl4c[(4 * tr + 0) * 32 + (kk ^ tr)];
        float4 xv1 = Xl4c[(4 * tr + 1) * 32 + (kk ^ tr)];
        float4 xv2 = Xl4c[(4 * tr + 2) * 32 + (kk ^ tr)];
        float4 xv3 = Xl4c[(4 * tr + 3) * 32 + (kk ^ tr)];
        float4 w0 = Wl4c[(4 * kk + 0) * 16 + tc];
        float4 w1 = Wl4c[(4 * kk + 1) * 16 + tc];
        float4 w2 = Wl4c[(4 * kk + 2) * 16 + tc];
        float4 w3 = Wl4c[(4 * kk + 3) * 16 + tc];
        fma4(acc0, xv0.x, w0); fma4(acc0, xv0.y, w1); fma4(acc0, xv0.z, w2); fma4(acc0, xv0.w, w3);
        fma4(acc1, xv1.x, w0); fma4(acc1, xv1.y, w1); fma4(acc1, xv1.z, w2); fma4(acc1, xv1.w, w3);
        fma4(acc2, xv2.x, w0); fma4(acc2, xv2.y, w1); fma4(acc2, xv2.z, w2); fma4(acc2, xv2.w, w3);
        fma4(acc3, xv3.x, w0); fma4(acc3, xv3.y, w1); fma4(acc3, xv3.z, w2); fma4(acc3, xv3.w, w3);
    }

    int gr = base + 4 * tr;
#pragma unroll
    for (int k = 0; k < 4; ++k) {
        int r = gr + k;
        if (r < N) {
            float d = dinv[r];
            float4 a = (k == 0) ? acc0 : (k == 1) ? acc1 : (k == 2) ? acc2 : acc3;
            ushort4 o = make_ushort4(f2bf(a.x * d), f2bf(a.y * d), f2bf(a.z * d), f2bf(a.w * d));
            *(ushort4*)(&xwb[(size_t)r * F1 + 4 * tc]) = o;
        }
    }
}

// gemm2: hwb = (relu(h) @ W2) * dinv[row], stored bf16. tile 128x32, thread = 4x4.
__global__ __launch_bounds__(256) void gemm2(const float* __restrict__ h,
                                             const float* __restrict__ W,
                                             const float* __restrict__ dinv,
                                             ushort_t* __restrict__ hwb, int N) {
    __shared__ float Hl[128 * F1];  // 32KB, swizzled
    __shared__ float Wl[F1 * F2];   // 8KB
    int tid = threadIdx.x;
    int base = blockIdx.x * 128;

    const float4* W4 = (const float4*)W;
    float4* Wl4 = (float4*)Wl;
#pragma unroll
    for (int i = 0; i < 2; ++i) Wl4[tid + 256 * i] = W4[tid + 256 * i];

    float4* Hl4 = (float4*)Hl;
#pragma unroll
    for (int i = 0; i < 8; ++i) {
        int idx = tid + 256 * i;
        int r = idx >> 4, c4 = idx & 15;
        int gr = base + r;
        float4 v = (gr < N) ? ((const float4*)h)[(size_t)gr * 16 + c4]
                            : make_float4(0.f, 0.f, 0.f, 0.f);
        v.x = fmaxf(v.x, 0.f); v.y = fmaxf(v.y, 0.f);
        v.z = fmaxf(v.z, 0.f); v.w = fmaxf(v.w, 0.f);
        Hl4[r * 16 + (c4 ^ ((r >> 2) & 15))] = v;
    }
    __syncthreads();

    int tc = tid & 7, tr = tid >> 3;
    float4 acc0 = make_float4(0.f, 0.f, 0.f, 0.f);
    float4 acc1 = acc0, acc2 = acc0, acc3 = acc0;
    const float4* Wl4c = (const float4*)Wl;
    const float4* Hl4c = (const float4*)Hl;

#pragma unroll 4
    for (int kk = 0; kk < 16; ++kk) {
        int sw = kk ^ (tr & 15);
        float4 xv0 = Hl4c[(4 * tr + 0) * 16 + sw];
        float4 xv1 = Hl4c[(4 * tr + 1) * 16 + sw];
        float4 xv2 = Hl4c[(4 * tr + 2) * 16 + sw];
        float4 xv3 = Hl4c[(4 * tr + 3) * 16 + sw];
        float4 w0 = Wl4c[(4 * kk + 0) * 8 + tc];
        float4 w1 = Wl4c[(4 * kk + 1) * 8 + tc];
        float4 w2 = Wl4c[(4 * kk + 2) * 8 + tc];
        float4 w3 = Wl4c[(4 * kk + 3) * 8 + tc];
        fma4(acc0, xv0.x, w0); fma4(acc0, xv0.y, w1); fma4(acc0, xv0.z, w2); fma4(acc0, xv0.w, w3);
        fma4(acc1, xv1.x, w0); fma4(acc1, xv1.y, w1); fma4(acc1, xv1.z, w2); fma4(acc1, xv1.w, w3);
        fma4(acc2, xv2.x, w0); fma4(acc2, xv2.y, w1); fma4(acc2, xv2.z, w2); fma4(acc2, xv2.w, w3);
        fma4(acc3, xv3.x, w0); fma4(acc3, xv3.y, w1); fma4(acc3, xv3.z, w2); fma4(acc3, xv3.w, w3);
    }

    int gr = base + 4 * tr;
#pragma unroll
    for (int k = 0; k < 4; ++k) {
        int r = gr + k;
        if (r < N) {
            float d = dinv[r];
            float4 a = (k == 0) ? acc0 : (k == 1) ? acc1 : (k == 2) ? acc2 : acc3;
            ushort4 o = make_ushort4(f2bf(a.x * d), f2bf(a.y * d), f2bf(a.z * d), f2bf(a.w * d));
            *(ushort4*)(&hwb[(size_t)r * F2 + 4 * tc]) = o;
        }
    }
}

// ================= layer 1 aggregation: one wave per node =================
// out[i] = dinv[i] * (scaled[i] + sum_e scaled[row_e]) + b, scaled = bf16(xw*dinv)
__global__ void agg1(const int* __restrict__ ptr, const int* __restrict__ erow,
                     const ushort_t* __restrict__ xwb, const float* __restrict__ dinv,
                     const float* __restrict__ b, float* __restrict__ out, int N) {
    int t = blockIdx.x * 256 + threadIdx.x;
    int i = t >> 6, j = t & 63;
    if (i >= N) return;
    float acc = bf2f(xwb[(size_t)i * F1 + j]);   // scaled self term
    int e = ptr[i], end = ptr[i + 1];
    for (; e + 3 < end; e += 4) {
        int r0 = erow[e], r1 = erow[e + 1], r2 = erow[e + 2], r3 = erow[e + 3];
        float v0 = bf2f(xwb[(size_t)r0 * F1 + j]);
        float v1 = bf2f(xwb[(size_t)r1 * F1 + j]);
        float v2 = bf2f(xwb[(size_t)r2 * F1 + j]);
        float v3 = bf2f(xwb[(size_t)r3 * F1 + j]);
        acc += v0; acc += v1; acc += v2; acc += v3;
    }
    for (; e < end; ++e) acc += bf2f(xwb[(size_t)erow[e] * F1 + j]);
    out[(size_t)i * F1 + j] = acc * dinv[i] + b[j];
}

// ================= layer 2 aggregation + fused log_softmax =================
__global__ void agg2_lsm(const int* __restrict__ ptr, const int* __restrict__ erow,
                         const ushort_t* __restrict__ hwb, const float* __restrict__ dinv,
                         const float* __restrict__ b, float* __restrict__ out, int N) {
    int t = blockIdx.x * 256 + threadIdx.x;
    int i = t >> 5, j = t & 31;
    if (i >= N) return;
    float acc = bf2f(hwb[(size_t)i * F2 + j]);
    int e = ptr[i], end = ptr[i + 1];
    for (; e + 3 < end; e += 4) {
        int r0 = erow[e], r1 = erow[e + 1], r2 = erow[e + 2], r3 = erow[e + 3];
        float v0 = bf2f(hwb[(size_t)r0 * F2 + j]);
        float v1 = bf2f(hwb[(size_t)r1 * F2 + j]);
        float v2 = bf2f(hwb[(size_t)r2 * F2 + j]);
        float v3 = bf2f(hwb[(size_t)r3 * F2 + j]);
        acc += v0; acc += v1; acc += v2; acc += v3;
    }
    for (; e < end; ++e) acc += bf2f(hwb[(size_t)erow[e] * F2 + j]);
    acc = acc * dinv[i] + b[j];
    float m = acc;
    for (int off = 16; off; off >>= 1) m = fmaxf(m, __shfl_xor(m, off, 32));
    float s = expf(acc - m);
    for (int off = 16; off; off >>= 1) s += __shfl_xor(s, off, 32);
    out[(size_t)i * F2 + j] = acc - m - logf(s);
}

extern "C" void kernel_launch(void* const* d_in, const int* in_sizes, int n_in,
                              void* d_out, int out_size, void* d_ws, size_t ws_size,
                              hipStream_t stream) {
    const float* x  = (const float*)d_in[0];
    const int*   ei = (const int*)d_in[1];
    const float* W1 = (const float*)d_in[2];
    const float* b1 = (const float*)d_in[3];
    const float* W2 = (const float*)d_in[4];
    const float* b2 = (const float*)d_in[5];

    int N = in_sizes[0] / F0;
    int E = in_sizes[1] / 2;
    const int* row = ei;
    const int* col = ei + E;

    size_t Np = ((size_t)N + 63) & ~(size_t)63;
    size_t Ep = ((size_t)E + 63) & ~(size_t)63;
    int*      cnt     = (int*)d_ws;                  // Np (reused as cur)
    int*      ptr     = cnt + Np;                    // Np+64
    float*    dinv    = (float*)(ptr + Np + 64);     // Np
    int*      partial = (int*)(dinv + Np);           // 1024
    int*      erow    = partial + 1024;              // Ep
    ushort_t* xwb     = (ushort_t*)(erow + Ep);      // Np*64 bf16 (reused as hwb)
    float*    out1    = (float*)(xwb + Np * F1);     // N*64 f32
    int*      cur     = cnt;
    ushort_t* hwb     = xwb;
    float*    out2    = (float*)d_out;

    int nbN  = (N + 255) / 256;
    int nbN1 = (N + 256) / 256;
    int nbE  = (E + 255) / 256;

    hipMemsetAsync(cnt, 0, (size_t)N * sizeof(int), stream);
    count_deg<<<nbE, 256, 0, stream>>>(col, cnt, E);
    scan_partial<<<nbN, 256, 0, stream>>>(cnt, partial, N);
    scan_block<<<1, 1024, 0, stream>>>(partial, nbN);
    scan_final<<<nbN1, 256, 0, stream>>>(cnt, partial, ptr, cur, dinv, N, E);
    edge_fill<<<nbE, 256, 0, stream>>>(row, col, cur, erow, E);

    gemm1<<<(N + 63) / 64, 256, 0, stream>>>(x, W1, dinv, xwb, N);
    agg1<<<(int)(((size_t)N * F1 + 255) / 256), 256, 0, stream>>>(ptr, erow, xwb, dinv, b1, out1, N);

    gemm2<<<(N + 127) / 128, 256, 0, stream>>>(out1, W2, dinv, hwb, N);
    agg2_lsm<<<(int)(((size_t)N * F2 + 255) / 256), 256, 0, stream>>>(ptr, erow, hwb, dinv, b2, out2, N);
}

// Round 8
// 179.400 us; speedup vs baseline: 1.2332x; 1.1458x over previous
//
#include <hip/hip_runtime.h>

#define F0 128
#define F1 64
#define F2 32

typedef unsigned short ushort_t;
typedef unsigned int uint_t;

__device__ __forceinline__ ushort_t f2bf(float f) {   // f32 -> bf16 RNE
    uint_t u = __float_as_uint(f);
    return (ushort_t)((u + 0x7FFFu + ((u >> 16) & 1u)) >> 16);
}
__device__ __forceinline__ float bf2f(ushort_t u) {   // bf16 -> f32
    return __uint_as_float((uint_t)u << 16);
}

// ================= CSR build =================
__global__ void count_deg(const int* __restrict__ col, int* cnt, int E) {
    int e = blockIdx.x * 256 + threadIdx.x;
    if (e < E) atomicAdd(&cnt[col[e]], 1);
}

__global__ void scan_partial(const int* __restrict__ cnt, int* __restrict__ partial, int N) {
    __shared__ int red[256];
    int i = blockIdx.x * 256 + threadIdx.x;
    red[threadIdx.x] = (i < N) ? cnt[i] : 0;
    __syncthreads();
    for (int off = 128; off; off >>= 1) {
        if (threadIdx.x < off) red[threadIdx.x] += red[threadIdx.x + off];
        __syncthreads();
    }
    if (threadIdx.x == 0) partial[blockIdx.x] = red[0];
}

__global__ __launch_bounds__(1024) void scan_block(int* partial, int nb) {
    __shared__ int s[1024];
    int t = threadIdx.x;
    int v = (t < nb) ? partial[t] : 0;
    s[t] = v;
    __syncthreads();
    for (int off = 1; off < 1024; off <<= 1) {
        int u = (t >= off) ? s[t - off] : 0;
        __syncthreads();
        s[t] += u;
        __syncthreads();
    }
    if (t < nb) partial[t] = s[t] - v;
}

// cur may alias cnt: each element read once before any write.
__global__ void scan_final(const int* __restrict__ cnt, const int* __restrict__ partial,
                           int* __restrict__ ptr, int* __restrict__ cur,
                           float* __restrict__ dinv, int N, int E) {
    __shared__ int s[256];
    int t = threadIdx.x;
    int i = blockIdx.x * 256 + t;
    int v = (i < N) ? cnt[i] : 0;
    s[t] = v;
    __syncthreads();
    for (int off = 1; off < 256; off <<= 1) {
        int u = (t >= off) ? s[t - off] : 0;
        __syncthreads();
        s[t] += u;
        __syncthreads();
    }
    if (i < N) {
        int p = partial[blockIdx.x] + s[t] - v;
        ptr[i] = p;
        cur[i] = p;
        dinv[i] = rsqrtf((float)(v + 1));
    } else if (i == N) {
        ptr[N] = E;
    }
}

// XCD-partitioned counting-sort fill. Block b handles col range (b&7) and
// edge chunk (b>>3). Under round-robin blockIdx->XCD dispatch, each erow
// region is written by exactly one XCD -> no cross-XCD line churn.
__global__ void edge_fill(const int* __restrict__ row, const int* __restrict__ col,
                          int* cur, int* __restrict__ erow, int E, int cpx) {
    int x = blockIdx.x & 7;
    int lo = x * cpx, hi = lo + cpx;
    int nchunks = gridDim.x >> 3;
    int stride = nchunks * 256;
    for (int e = (blockIdx.x >> 3) * 256 + threadIdx.x; e < E; e += stride) {
        int c = col[e];
        if (c >= lo && c < hi) {
            int pos = atomicAdd(&cur[c], 1);
            erow[pos] = row[e];
        }
    }
}

// ================= register-tiled GEMMs =================
__device__ __forceinline__ void fma4(float4& a, float xs, const float4& wv) {
    a.x = fmaf(xs, wv.x, a.x);
    a.y = fmaf(xs, wv.y, a.y);
    a.z = fmaf(xs, wv.z, a.z);
    a.w = fmaf(xs, wv.w, a.w);
}

// gemm1: xwb = (x @ W1) * dinv[row], stored bf16. tile 64x64, thread = 4x4.
__global__ __launch_bounds__(256) void gemm1(const float* __restrict__ x,
                                             const float* __restrict__ W,
                                             const float* __restrict__ dinv,
                                             ushort_t* __restrict__ xwb, int N) {
    __shared__ float Xl[64 * F0];   // 32KB, swizzled
    __shared__ float Wl[F0 * F1];   // 32KB, linear [k][64]
    int tid = threadIdx.x;
    int base = blockIdx.x * 64;

    const float4* W4 = (const float4*)W;
    float4* Wl4 = (float4*)Wl;
#pragma unroll
    for (int i = 0; i < 8; ++i) Wl4[tid + 256 * i] = W4[tid + 256 * i];

    float4* Xl4 = (float4*)Xl;
#pragma unroll
    for (int i = 0; i < 8; ++i) {
        int idx = tid + 256 * i;
        int r = idx >> 5, c4 = idx & 31;
        int gr = base + r;
        float4 v = (gr < N) ? ((const float4*)x)[(size_t)gr * 32 + c4]
                            : make_float4(0.f, 0.f, 0.f, 0.f);
        Xl4[r * 32 + (c4 ^ (r >> 2))] = v;
    }
    __syncthreads();

    int tc = tid & 15, tr = tid >> 4;
    float4 acc0 = make_float4(0.f, 0.f, 0.f, 0.f);
    float4 acc1 = acc0, acc2 = acc0, acc3 = acc0;
    const float4* Wl4c = (const float4*)Wl;
    const float4* Xl4c = (const float4*)Xl;

#pragma unroll 4
    for (int kk = 0; kk < 32; ++kk) {
        float4 xv0 = Xl4c[(4 * tr + 0) * 32 + (kk ^ tr)];
        float4 xv1 = Xl4c[(4 * tr + 1) * 32 + (kk ^ tr)];
        float4 xv2 = Xl4c[(4 * tr + 2) * 32 + (kk ^ tr)];
        float4 xv3 = Xl4c[(4 * tr + 3) * 32 + (kk ^ tr)];
        float4 w0 = Wl4c[(4 * kk + 0) * 16 + tc];
        float4 w1 = Wl4c[(4 * kk + 1) * 16 + tc];
        float4 w2 = Wl4c[(4 * kk + 2) * 16 + tc];
        float4 w3 = Wl4c[(4 * kk + 3) * 16 + tc];
        fma4(acc0, xv0.x, w0); fma4(acc0, xv0.y, w1); fma4(acc0, xv0.z, w2); fma4(acc0, xv0.w, w3);
        fma4(acc1, xv1.x, w0); fma4(acc1, xv1.y, w1); fma4(acc1, xv1.z, w2); fma4(acc1, xv1.w, w3);
        fma4(acc2, xv2.x, w0); fma4(acc2, xv2.y, w1); fma4(acc2, xv2.z, w2); fma4(acc2, xv2.w, w3);
        fma4(acc3, xv3.x, w0); fma4(acc3, xv3.y, w1); fma4(acc3, xv3.z, w2); fma4(acc3, xv3.w, w3);
    }

    int gr = base + 4 * tr;
#pragma unroll
    for (int k = 0; k < 4; ++k) {
        int r = gr + k;
        if (r < N) {
            float d = dinv[r];
            float4 a = (k == 0) ? acc0 : (k == 1) ? acc1 : (k == 2) ? acc2 : acc3;
            ushort4 o = make_ushort4(f2bf(a.x * d), f2bf(a.y * d), f2bf(a.z * d), f2bf(a.w * d));
            *(ushort4*)(&xwb[(size_t)r * F1 + 4 * tc]) = o;
        }
    }
}

// gemm2: hwb = (relu(h) @ W2) * dinv[row], stored bf16. tile 128x32, thread = 4x4.
__global__ __launch_bounds__(256) void gemm2(const float* __restrict__ h,
                                             const float* __restrict__ W,
                                             const float* __restrict__ dinv,
                                             ushort_t* __restrict__ hwb, int N) {
    __shared__ float Hl[128 * F1];  // 32KB, swizzled
    __shared__ float Wl[F1 * F2];   // 8KB
    int tid = threadIdx.x;
    int base = blockIdx.x * 128;

    const float4* W4 = (const float4*)W;
    float4* Wl4 = (float4*)Wl;
#pragma unroll
    for (int i = 0; i < 2; ++i) Wl4[tid + 256 * i] = W4[tid + 256 * i];

    float4* Hl4 = (float4*)Hl;
#pragma unroll
    for (int i = 0; i < 8; ++i) {
        int idx = tid + 256 * i;
        int r = idx >> 4, c4 = idx & 15;
        int gr = base + r;
        float4 v = (gr < N) ? ((const float4*)h)[(size_t)gr * 16 + c4]
                            : make_float4(0.f, 0.f, 0.f, 0.f);
        v.x = fmaxf(v.x, 0.f); v.y = fmaxf(v.y, 0.f);
        v.z = fmaxf(v.z, 0.f); v.w = fmaxf(v.w, 0.f);
        Hl4[r * 16 + (c4 ^ ((r >> 2) & 15))] = v;
    }
    __syncthreads();

    int tc = tid & 7, tr = tid >> 3;
    float4 acc0 = make_float4(0.f, 0.f, 0.f, 0.f);
    float4 acc1 = acc0, acc2 = acc0, acc3 = acc0;
    const float4* Wl4c = (const float4*)Wl;
    const float4* Hl4c = (const float4*)Hl;

#pragma unroll 4
    for (int kk = 0; kk < 16; ++kk) {
        int sw = kk ^ (tr & 15);
        float4 xv0 = Hl4c[(4 * tr + 0) * 16 + sw];
        float4 xv1 = Hl4c[(4 * tr + 1) * 16 + sw];
        float4 xv2 = Hl4c[(4 * tr + 2) * 16 + sw];
        float4 xv3 = Hl4c[(4 * tr + 3) * 16 + sw];
        float4 w0 = Wl4c[(4 * kk + 0) * 8 + tc];
        float4 w1 = Wl4c[(4 * kk + 1) * 8 + tc];
        float4 w2 = Wl4c[(4 * kk + 2) * 8 + tc];
        float4 w3 = Wl4c[(4 * kk + 3) * 8 + tc];
        fma4(acc0, xv0.x, w0); fma4(acc0, xv0.y, w1); fma4(acc0, xv0.z, w2); fma4(acc0, xv0.w, w3);
        fma4(acc1, xv1.x, w0); fma4(acc1, xv1.y, w1); fma4(acc1, xv1.z, w2); fma4(acc1, xv1.w, w3);
        fma4(acc2, xv2.x, w0); fma4(acc2, xv2.y, w1); fma4(acc2, xv2.z, w2); fma4(acc2, xv2.w, w3);
        fma4(acc3, xv3.x, w0); fma4(acc3, xv3.y, w1); fma4(acc3, xv3.z, w2); fma4(acc3, xv3.w, w3);
    }

    int gr = base + 4 * tr;
#pragma unroll
    for (int k = 0; k < 4; ++k) {
        int r = gr + k;
        if (r < N) {
            float d = dinv[r];
            float4 a = (k == 0) ? acc0 : (k == 1) ? acc1 : (k == 2) ? acc2 : acc3;
            ushort4 o = make_ushort4(f2bf(a.x * d), f2bf(a.y * d), f2bf(a.z * d), f2bf(a.w * d));
            *(ushort4*)(&hwb[(size_t)r * F2 + 4 * tc]) = o;
        }
    }
}

// ================= layer 1 aggregation: one wave per node =================
// out[i] = dinv[i] * (scaled[i] + sum_e scaled[row_e]) + b, scaled = bf16(xw*dinv)
__global__ void agg1(const int* __restrict__ ptr, const int* __restrict__ erow,
                     const ushort_t* __restrict__ xwb, const float* __restrict__ dinv,
                     const float* __restrict__ b, float* __restrict__ out, int N) {
    int t = blockIdx.x * 256 + threadIdx.x;
    int i = t >> 6, j = t & 63;
    if (i >= N) return;
    float acc = bf2f(xwb[(size_t)i * F1 + j]);   // scaled self term
    int e = ptr[i], end = ptr[i + 1];
    for (; e + 3 < end; e += 4) {
        int r0 = erow[e], r1 = erow[e + 1], r2 = erow[e + 2], r3 = erow[e + 3];
        float v0 = bf2f(xwb[(size_t)r0 * F1 + j]);
        float v1 = bf2f(xwb[(size_t)r1 * F1 + j]);
        float v2 = bf2f(xwb[(size_t)r2 * F1 + j]);
        float v3 = bf2f(xwb[(size_t)r3 * F1 + j]);
        acc += v0; acc += v1; acc += v2; acc += v3;
    }
    for (; e < end; ++e) acc += bf2f(xwb[(size_t)erow[e] * F1 + j]);
    out[(size_t)i * F1 + j] = acc * dinv[i] + b[j];
}

// ================= layer 2 aggregation + fused log_softmax =================
__global__ void agg2_lsm(const int* __restrict__ ptr, const int* __restrict__ erow,
                         const ushort_t* __restrict__ hwb, const float* __restrict__ dinv,
                         const float* __restrict__ b, float* __restrict__ out, int N) {
    int t = blockIdx.x * 256 + threadIdx.x;
    int i = t >> 5, j = t & 31;
    if (i >= N) return;
    float acc = bf2f(hwb[(size_t)i * F2 + j]);
    int e = ptr[i], end = ptr[i + 1];
    for (; e + 3 < end; e += 4) {
        int r0 = erow[e], r1 = erow[e + 1], r2 = erow[e + 2], r3 = erow[e + 3];
        float v0 = bf2f(hwb[(size_t)r0 * F2 + j]);
        float v1 = bf2f(hwb[(size_t)r1 * F2 + j]);
        float v2 = bf2f(hwb[(size_t)r2 * F2 + j]);
        float v3 = bf2f(hwb[(size_t)r3 * F2 + j]);
        acc += v0; acc += v1; acc += v2; acc += v3;
    }
    for (; e < end; ++e) acc += bf2f(hwb[(size_t)erow[e] * F2 + j]);
    acc = acc * dinv[i] + b[j];
    float m = acc;
    for (int off = 16; off; off >>= 1) m = fmaxf(m, __shfl_xor(m, off, 32));
    float s = expf(acc - m);
    for (int off = 16; off; off >>= 1) s += __shfl_xor(s, off, 32);
    out[(size_t)i * F2 + j] = acc - m - logf(s);
}

extern "C" void kernel_launch(void* const* d_in, const int* in_sizes, int n_in,
                              void* d_out, int out_size, void* d_ws, size_t ws_size,
                              hipStream_t stream) {
    const float* x  = (const float*)d_in[0];
    const int*   ei = (const int*)d_in[1];
    const float* W1 = (const float*)d_in[2];
    const float* b1 = (const float*)d_in[3];
    const float* W2 = (const float*)d_in[4];
    const float* b2 = (const float*)d_in[5];

    int N = in_sizes[0] / F0;
    int E = in_sizes[1] / 2;
    const int* row = ei;
    const int* col = ei + E;

    size_t Np = ((size_t)N + 63) & ~(size_t)63;
    size_t Ep = ((size_t)E + 63) & ~(size_t)63;
    int*      cnt     = (int*)d_ws;                  // Np (reused as cur)
    int*      ptr     = cnt + Np;                    // Np+64
    float*    dinv    = (float*)(ptr + Np + 64);     // Np
    int*      partial = (int*)(dinv + Np);           // 1024
    int*      erow    = partial + 1024;              // Ep
    ushort_t* xwb     = (ushort_t*)(erow + Ep);      // Np*64 bf16 (reused as hwb)
    float*    out1    = (float*)(xwb + Np * F1);     // N*64 f32
    int*      cur     = cnt;
    ushort_t* hwb     = xwb;
    float*    out2    = (float*)d_out;

    int nbN  = (N + 255) / 256;
    int nbN1 = (N + 256) / 256;
    int nbE  = (E + 255) / 256;
    int cpx  = (N + 7) / 8;   // cols per XCD range

    hipMemsetAsync(cnt, 0, (size_t)N * sizeof(int), stream);
    count_deg<<<nbE, 256, 0, stream>>>(col, cnt, E);
    scan_partial<<<nbN, 256, 0, stream>>>(cnt, partial, N);
    scan_block<<<1, 1024, 0, stream>>>(partial, nbN);
    scan_final<<<nbN1, 256, 0, stream>>>(cnt, partial, ptr, cur, dinv, N, E);
    edge_fill<<<256 * 8, 256, 0, stream>>>(row, col, cur, erow, E, cpx);

    gemm1<<<(N + 63) / 64, 256, 0, stream>>>(x, W1, dinv, xwb, N);
    agg1<<<(int)(((size_t)N * F1 + 255) / 256), 256, 0, stream>>>(ptr, erow, xwb, dinv, b1, out1, N);

    gemm2<<<(N + 127) / 128, 256, 0, stream>>>(out1, W2, dinv, hwb, N);
    agg2_lsm<<<(int)(((size_t)N * F2 + 255) / 256), 256, 0, stream>>>(ptr, erow, hwb, dinv, b2, out2, N);
}